// Round 8
// baseline (266.794 us; speedup 1.0000x reference)
//
#include <hip/hip_runtime.h>

#define DIM 768
#define TD 2304
#define NB 8
#define NS 4096
#define NE 6

// ws layout (float offsets)
#define OFF_QC3    0            // [2304][20]: per col, 0-5 Q, 6-11 P, 12-17 A1, 18-19 pad
#define OFF_A2F    46080        // [2304][6] delta-mean fold
#define OFF_CB0    59904        // [16]
#define OFF_ACCSUM 59920        // [8][6] + pad = 64
#define OFF_CONSTB 59984        // [8][6] + pad = 64
#define OFF_QP     60048        // [3][32768][12]

// ---------------- kernel B: fold all coefficient matrices (+cb0, +accsum zero) ----
__global__ __launch_bounds__(256) void k_fold(
    const float* __restrict__ Wspat, const float* __restrict__ Wtemp,
    const float* __restrict__ Wsync, const float* __restrict__ Wroute,
    const float* __restrict__ Wglob, const float* __restrict__ bglob,
    const float* __restrict__ broute, const float* __restrict__ bspat,
    const float* __restrict__ btemp, const float* __restrict__ bsync,
    float* __restrict__ Qc3, float* __restrict__ A2F,
    float* __restrict__ cb0, float* __restrict__ accsum)
{
    __shared__ float lwr[288 * NE];
    __shared__ float lgf[224 * NE];
    const int t = threadIdx.x;
    for (int i = t; i < 288 * NE; i += 256) lwr[i] = Wroute[i];
    __syncthreads();
    if (t < 224) {
        float g[NE] = {0, 0, 0, 0, 0, 0};
        for (int o = 0; o < 64; ++o) {
            const float w = Wglob[t * 64 + o];
            #pragma unroll
            for (int e = 0; e < NE; ++e) g[e] += w * lwr[(224 + o) * NE + e];
        }
        #pragma unroll
        for (int e = 0; e < NE; ++e) lgf[t * NE + e] = g[e];
    }
    __syncthreads();
    if (blockIdx.x == 0) {
        if (t < NE) {
            float a = broute[t];
            for (int o = 0; o < 64; ++o)  a += bglob[o] * lwr[(224 + o) * NE + t];
            for (int o = 0; o < 128; ++o) a += bspat[o] * (lwr[o * NE + t] + lgf[o * NE + t]);
            for (int o = 0; o < 64; ++o)  a += btemp[o] * (lwr[(128 + o) * NE + t] + lgf[(128 + o) * NE + t]);
            for (int o = 0; o < 32; ++o)  a += bsync[o] * (lwr[(192 + o) * NE + t] + lgf[(192 + o) * NE + t]);
            cb0[t] = a;
        }
        if (t >= 128 && t < 192) accsum[t - 128] = 0.f;
    }

    const int d = blockIdx.x * 256 + t;          // exactly 2304 threads
    const int st = d / DIM, dd = d - st * DIM;

    float p[NE] = {0, 0, 0, 0, 0, 0}, a2[NE] = {0, 0, 0, 0, 0, 0};
    for (int o = 0; o < 64; ++o) {
        const float w = Wtemp[d * 64 + o];
        #pragma unroll
        for (int e = 0; e < NE; ++e) {
            p[e]  += w * lwr[(128 + o) * NE + e];
            a2[e] += w * lgf[(128 + o) * NE + e];
        }
    }
    float qq[NE], a1[NE];
    #pragma unroll
    for (int e = 0; e < NE; ++e) { qq[e] = p[e]; a1[e] = 0.f; }
    for (int o = 0; o < 128; ++o) {
        const float w = Wspat[d * 128 + o];
        #pragma unroll
        for (int e = 0; e < NE; ++e) {
            qq[e] += w * lwr[o * NE + e];
            a1[e] += w * lgf[o * NE + e];
        }
    }
    if (st != 0) {
        const float sg = (st == 1) ? 1.f : -1.f;
        for (int o = 0; o < 32; ++o) {
            const float w = sg * Wsync[dd * 32 + o];
            #pragma unroll
            for (int e = 0; e < NE; ++e) {
                qq[e] += w * lwr[(192 + o) * NE + e];
                a1[e] += w * lgf[(192 + o) * NE + e];
            }
        }
    }
    #pragma unroll
    for (int e = 0; e < NE; ++e) {
        Qc3[(size_t)d * 20 + e]      = qq[e];
        Qc3[(size_t)d * 20 + 6 + e]  = p[e];
        Qc3[(size_t)d * 20 + 12 + e] = a1[e];
        A2F[d * NE + e] = a2[e];
    }
}

// ---------------- kernel C: main streaming pass ----------------
// grid = 8b * 3st * 64rg = 1536 blocks; 256 thr = 4 waves. Block = 64 rows.
// Lane l = row. Wave w (readfirstlane-uniform) owns cols w*16..w*16+15 of each
// 64-col chunk -> coefficient addresses are WAVE-UNIFORM (scalar loads).
// Thread accumulates 18 outputs (Q6,P6,A1-6) for its row in registers; NO
// cross-lane ops in the loop. x staged global->reg->LDS [64][65] (pad -> free
// banks), double-buffered, 1 barrier/chunk. Cross-wave reduce once at end.
__global__ __launch_bounds__(256, 4) void k_main(
    const float* __restrict__ xt, const float* __restrict__ xa, const float* __restrict__ xv,
    const float* __restrict__ Qc3, float* __restrict__ accsum, float* __restrict__ qp)
{
    __shared__ float smem[2 * 64 * 65];    // 33.3 KB; reused for end-reduce
    const int t = threadIdx.x;
    const int l = t & 63;
    const int w = __builtin_amdgcn_readfirstlane(t >> 6);
    const int bid = blockIdx.x;
    const int rg = bid & 63;
    const int st = (bid >> 6) % 3;
    const int bb = bid / 192;

    const float* X = (st == 0) ? xt : ((st == 1) ? xa : xv);
    const int row0 = rg * 64;

    // staging: thread stages row t>>2, 16 cols at (t&3)*16 (64B/lane, coalesced)
    const int srow = t >> 2, scol = (t & 3) * 16;
    const float* gsrc = X + (size_t)(bb * NS + row0 + srow) * DIM + scol;
    const float* cbase = Qc3 + (size_t)st * DIM * 20;

    float* rb = smem;
    float* wb = smem + 64 * 65;

    float4 g0, g1, g2, g3;
    g0 = *(const float4*)(gsrc + 0);
    g1 = *(const float4*)(gsrc + 4);
    g2 = *(const float4*)(gsrc + 8);
    g3 = *(const float4*)(gsrc + 12);
    {
        float* wp = rb + srow * 65 + scol;
        *(float4*)(wp + 0) = g0; *(float4*)(wp + 4)  = g1;
        *(float4*)(wp + 8) = g2; *(float4*)(wp + 12) = g3;
    }
    __syncthreads();

    float aq[6] = {0, 0, 0, 0, 0, 0};
    float ap[6] = {0, 0, 0, 0, 0, 0};
    float ag[6] = {0, 0, 0, 0, 0, 0};

    #pragma unroll 1
    for (int c = 0; c < 12; ++c) {
        if (c < 11) {                       // issue next-chunk loads early
            const float* gs = gsrc + (c + 1) * 64;
            g0 = *(const float4*)(gs + 0);
            g1 = *(const float4*)(gs + 4);
            g2 = *(const float4*)(gs + 8);
            g3 = *(const float4*)(gs + 12);
        }
        const float* xr = rb + l * 65 + w * 16;
        const float* cw = cbase + (size_t)(c * 64 + w * 16) * 20;
        #pragma unroll
        for (int j = 0; j < 4; ++j) {
            const float4 xv = *(const float4*)(xr + j * 4);
            const float* cj = cw + j * 80;          // 4 cols * 20 floats
            #pragma unroll
            for (int e = 0; e < 6; ++e) {
                aq[e] += xv.x * cj[e];
                aq[e] += xv.y * cj[20 + e];
                aq[e] += xv.z * cj[40 + e];
                aq[e] += xv.w * cj[60 + e];
            }
            #pragma unroll
            for (int e = 0; e < 6; ++e) {
                ap[e] += xv.x * cj[6 + e];
                ap[e] += xv.y * cj[26 + e];
                ap[e] += xv.z * cj[46 + e];
                ap[e] += xv.w * cj[66 + e];
            }
            #pragma unroll
            for (int e = 0; e < 6; ++e) {
                ag[e] += xv.x * cj[12 + e];
                ag[e] += xv.y * cj[32 + e];
                ag[e] += xv.z * cj[52 + e];
                ag[e] += xv.w * cj[72 + e];
            }
        }
        if (c < 11) {
            float* wp = wb + srow * 65 + scol;
            *(float4*)(wp + 0) = g0; *(float4*)(wp + 4)  = g1;
            *(float4*)(wp + 8) = g2; *(float4*)(wp + 12) = g3;
        }
        __syncthreads();
        float* tp = rb; rb = wb; wb = tp;
    }

    // end-reduce across the 4 waves (once per kernel), reusing smem
    float* red = smem;
    {
        float* rp = red + (l * 4 + w) * 20;
        #pragma unroll
        for (int e = 0; e < 6; ++e) { rp[e] = aq[e]; rp[6 + e] = ap[e]; rp[12 + e] = ag[e]; }
    }
    __syncthreads();
    if (t < 64) {
        const float* r0 = red + (t * 4 + 0) * 20;
        const float* r1 = red + (t * 4 + 1) * 20;
        const float* r2 = red + (t * 4 + 2) * 20;
        const float* r3 = red + (t * 4 + 3) * 20;
        float q[6], p[6], a[6];
        #pragma unroll
        for (int e = 0; e < 6; ++e) {
            q[e] = r0[e] + r1[e] + r2[e] + r3[e];
            p[e] = r0[6 + e] + r1[6 + e] + r2[6 + e] + r3[6 + e];
            a[e] = r0[12 + e] + r1[12 + e] + r2[12 + e] + r3[12 + e];
        }
        float* dst = qp + ((size_t)(st * NB + bb) * NS + row0 + t) * 12;
        *(float4*)(dst + 0) = make_float4(q[0], q[1], q[2], q[3]);
        *(float4*)(dst + 4) = make_float4(q[4], q[5], p[0], p[1]);
        *(float4*)(dst + 8) = make_float4(p[2], p[3], p[4], p[5]);
        #pragma unroll
        for (int e = 0; e < 6; ++e) {
            float v = a[e];
            v += __shfl_xor(v, 1, 64);
            v += __shfl_xor(v, 2, 64);
            v += __shfl_xor(v, 4, 64);
            v += __shfl_xor(v, 8, 64);
            v += __shfl_xor(v, 16, 64);
            v += __shfl_xor(v, 32, 64);
            a[e] = v;
        }
        if (t == 0) {
            #pragma unroll
            for (int e = 0; e < 6; ++e) atomicAdd(&accsum[bb * NE + e], a[e]);
        }
    }
}

// ---------------- kernel D: per-batch global constant ----------------
__global__ __launch_bounds__(256) void k_const(
    const float* __restrict__ xt, const float* __restrict__ xa, const float* __restrict__ xv,
    const float* __restrict__ accsum, const float* __restrict__ A2F,
    const float* __restrict__ cb0, float* __restrict__ constb)
{
    const int b = blockIdx.x, t = threadIdx.x;
    const float* Xs[3] = { xt, xa, xv };
    float acc[NE] = {0, 0, 0, 0, 0, 0};
    for (int f = t; f < TD; f += 256) {
        const int st = f / DIM, dd = f - st * DIM;
        const float* Xp = Xs[st] + (size_t)b * NS * DIM;
        const float dm = Xp[(size_t)(NS - 1) * DIM + dd] - Xp[dd];
        const float* Ap = A2F + f * NE;
        #pragma unroll
        for (int e = 0; e < NE; ++e) acc[e] += dm * Ap[e];
    }
    #pragma unroll
    for (int e = 0; e < NE; ++e)
        for (int m = 1; m < 64; m <<= 1) acc[e] += __shfl_xor(acc[e], m, 64);
    __shared__ float wred[4][NE];
    if ((t & 63) == 0) {
        #pragma unroll
        for (int e = 0; e < NE; ++e) wred[t >> 6][e] = acc[e];
    }
    __syncthreads();
    if (t < NE) {
        const float inv = 1.f / 4096.f;
        const float dsum = wred[0][t] + wred[1][t] + wred[2][t] + wred[3][t];
        constb[b * NE + t] = cb0[t] + accsum[b * NE + t] * inv + dsum * inv;
    }
}

// ---------------- kernel E: combine q - shifted p + const ----------------
__global__ __launch_bounds__(256) void k_add(
    const float* __restrict__ qp, const float* __restrict__ constb, float* __restrict__ out)
{
    const int row = blockIdx.x * 256 + threadIdx.x;   // 32768 rows exact
    const int b = row >> 12, s = row & (NS - 1);
    const int rowp = (s == 0) ? row : row - 1;
    float o[NE];
    #pragma unroll
    for (int e = 0; e < NE; ++e) o[e] = constb[b * NE + e];
    #pragma unroll
    for (int st = 0; st < 3; ++st) {
        const float* qr = qp + ((size_t)st * NB * NS + row) * 12;
        const float* pr = qp + ((size_t)st * NB * NS + rowp) * 12;
        #pragma unroll
        for (int e = 0; e < NE; ++e) o[e] += qr[e] - pr[6 + e];
    }
    float* op = out + (size_t)row * NE;
    #pragma unroll
    for (int e = 0; e < NE; ++e) op[e] = o[e];
}

extern "C" void kernel_launch(void* const* d_in, const int* in_sizes, int n_in,
                              void* d_out, int out_size, void* d_ws, size_t ws_size,
                              hipStream_t stream)
{
    const float* xt     = (const float*)d_in[0];
    const float* xa     = (const float*)d_in[1];
    const float* xv     = (const float*)d_in[2];
    const float* Wspat  = (const float*)d_in[3];
    const float* bspat  = (const float*)d_in[4];
    const float* Wtemp  = (const float*)d_in[5];
    const float* btemp  = (const float*)d_in[6];
    const float* Wsync  = (const float*)d_in[7];
    const float* bsync  = (const float*)d_in[8];
    const float* Wglob  = (const float*)d_in[9];
    const float* bglob  = (const float*)d_in[10];
    const float* Wroute = (const float*)d_in[11];
    const float* broute = (const float*)d_in[12];
    float* out = (float*)d_out;

    float* ws     = (float*)d_ws;
    float* Qc3    = ws + OFF_QC3;
    float* A2F    = ws + OFF_A2F;
    float* cb0    = ws + OFF_CB0;
    float* accsum = ws + OFF_ACCSUM;
    float* constb = ws + OFF_CONSTB;
    float* qp     = ws + OFF_QP;

    k_fold<<<9, 256, 0, stream>>>(Wspat, Wtemp, Wsync, Wroute, Wglob, bglob,
                                  broute, bspat, btemp, bsync, Qc3, A2F, cb0, accsum);
    k_main<<<1536, 256, 0, stream>>>(xt, xa, xv, Qc3, accsum, qp);
    k_const<<<8, 256, 0, stream>>>(xt, xa, xv, accsum, A2F, cb0, constb);
    k_add<<<128, 256, 0, stream>>>(qp, constb, out);
}